// Round 1
// baseline (319.131 us; speedup 1.0000x reference)
//
#include <hip/hip_runtime.h>

// GetWeightMatrix: weight = 1 + 1.5 * sum_{5x5 shifts}(y_pad != argmax_c(x))
// x: [8, 21, 512, 512] f32, y: [8, 512, 512] i32, out: [8, 1, 512, 512] f32
//
// Latency-bound fix vs previous version:
//  - __launch_bounds__(256, 8): cap VGPR at 64 so all 8192 waves of the grid
//    are co-resident (8 waves/SIMD) -> full TLP to hide HBM latency.
//  - argmax processes channels in groups of 4 (max 16 load-regs in flight,
//    compiler pipelines next group's loads under current group's compares).
//  - y neighborhood: 3 aligned predicated int4 loads per row (12 ints covering
//    h-4..h+7) instead of 8 scalar predicated loads -> 15 vmem ops vs 40.
//  - non-temporal loads on x (read-once stream, don't thrash L2; y stays hot).

typedef float f32x4 __attribute__((ext_vector_type(4)));
typedef int   i32x4 __attribute__((ext_vector_type(4)));

constexpr int B = 8;
constexpr int C = 21;
constexpr int W = 512;
constexpr int H = 512;
constexpr int PIX = W * H;

__global__ __launch_bounds__(256, 8) void getweight_kernel(
    const float* __restrict__ x, const int* __restrict__ y,
    float* __restrict__ out)
{
    const int tid = blockIdx.x * blockDim.x + threadIdx.x;
    const int gpr = H / 4;        // 128 float4-groups per row
    const int gpi = W * gpr;      // 65536 groups per image
    const int b   = tid / gpi;
    const int rem = tid - b * gpi;
    const int w   = rem / gpr;
    const int h   = (rem - w * gpr) << 2;   // base h of this thread's 4 pixels

    // ---- argmax over 21 channels, 4 pixels at once ----
    // Channel 0 seeds; then 5 groups of 4 channels. Strict > keeps the FIRST
    // max index, matching jnp.argmax tie-break.
    const float* xp = x + (size_t)b * C * PIX + (size_t)w * H + h;
    f32x4 best = __builtin_nontemporal_load((const f32x4*)xp);
    int am0 = 0, am1 = 0, am2 = 0, am3 = 0;

#define ARGMAX_STEP(v, c)                                   \
    do {                                                    \
        if ((v)[0] > best[0]) { best[0] = (v)[0]; am0 = (c); } \
        if ((v)[1] > best[1]) { best[1] = (v)[1]; am1 = (c); } \
        if ((v)[2] > best[2]) { best[2] = (v)[2]; am2 = (c); } \
        if ((v)[3] > best[3]) { best[3] = (v)[3]; am3 = (c); } \
    } while (0)

#pragma unroll
    for (int g = 0; g < 5; ++g) {
        const int c0 = 4 * g + 1;
        f32x4 v0 = __builtin_nontemporal_load((const f32x4*)(xp + (size_t)(c0 + 0) * PIX));
        f32x4 v1 = __builtin_nontemporal_load((const f32x4*)(xp + (size_t)(c0 + 1) * PIX));
        f32x4 v2 = __builtin_nontemporal_load((const f32x4*)(xp + (size_t)(c0 + 2) * PIX));
        f32x4 v3 = __builtin_nontemporal_load((const f32x4*)(xp + (size_t)(c0 + 3) * PIX));
        ARGMAX_STEP(v0, c0 + 0);
        ARGMAX_STEP(v1, c0 + 1);
        ARGMAX_STEP(v2, c0 + 2);
        ARGMAX_STEP(v3, c0 + 3);
    }
#undef ARGMAX_STEP

    // ---- 5x5 neighborhood mismatch count vs y (zero-pad => OOB label 0) ----
    // Per row di: 3 aligned int4 loads covering h-4 .. h+7 (12 ints), the
    // needed window h-2 .. h+5 is elements 2..9. Out-of-range chunks are
    // replaced with 0 (= pad label), which is exactly the Unfold zero-pad:
    //   chunk0 (h-4..h-1) invalid iff h==0  -> needed elems h-2,h-1 are OOB -> 0 ok
    //   chunk2 (h+4..h+7) invalid iff h==H-4 -> needed elems h+4,h+5 are OOB -> 0 ok
    const int* yb = y + b * PIX;
    const i32x4 zero4 = {0, 0, 0, 0};
    int cnt0 = 0, cnt1 = 0, cnt2 = 0, cnt3 = 0;
#pragma unroll
    for (int di = 0; di < 5; ++di) {
        const int ww = w + di - 2;
        const bool wok = (unsigned)ww < (unsigned)W;   // wave-uniform
        const int* yrow = yb + ww * H;
        i32x4 ca = (wok && h >= 4)       ? *(const i32x4*)(yrow + h - 4) : zero4;
        i32x4 cb = wok                   ? *(const i32x4*)(yrow + h)     : zero4;
        i32x4 cc = (wok && h <= H - 8)   ? *(const i32x4*)(yrow + h + 4) : zero4;
        int yr[12] = {ca[0], ca[1], ca[2], ca[3],
                      cb[0], cb[1], cb[2], cb[3],
                      cc[0], cc[1], cc[2], cc[3]};
#pragma unroll
        for (int dj = 0; dj < 5; ++dj) {
            cnt0 += (yr[2 + 0 + dj] != am0) ? 1 : 0;
            cnt1 += (yr[2 + 1 + dj] != am1) ? 1 : 0;
            cnt2 += (yr[2 + 2 + dj] != am2) ? 1 : 0;
            cnt3 += (yr[2 + 3 + dj] != am3) ? 1 : 0;
        }
    }

    f32x4 res;
    res[0] = 1.0f + 1.5f * (float)cnt0;
    res[1] = 1.0f + 1.5f * (float)cnt1;
    res[2] = 1.0f + 1.5f * (float)cnt2;
    res[3] = 1.0f + 1.5f * (float)cnt3;
    __builtin_nontemporal_store(res, (f32x4*)(out + (size_t)b * PIX + (size_t)w * H + h));
}

extern "C" void kernel_launch(void* const* d_in, const int* in_sizes, int n_in,
                              void* d_out, int out_size, void* d_ws, size_t ws_size,
                              hipStream_t stream) {
    const float* x = (const float*)d_in[0];   // [8,21,512,512] f32
    const int*   y = (const int*)d_in[1];     // [8,512,512] i32
    float* out = (float*)d_out;               // [8,1,512,512] f32

    const int total_threads = B * PIX / 4;    // 524288
    const int block = 256;
    const int grid = total_threads / block;   // 2048
    getweight_kernel<<<grid, block, 0, stream>>>(x, y, out);
}

// Round 4
// 248.993 us; speedup vs baseline: 1.2817x; 1.2817x over previous
//
#include <hip/hip_runtime.h>

// GetWeightMatrix: weight = 1 + 1.5 * sum_{5x5 shifts}(y_pad != argmax_c(x))
// x: [8, 21, 512, 512] f32, y: [8, 512, 512] i32, out: [8, 1, 512, 512] f32
//
// Round-3 resubmit (rounds 2 & 3 were broker/container infra failures, before
// kernel compile — no diagnostics, no dispatches; round-1 acquire already took
// 90 s, fleet is flaky). Experiment under test is UNCHANGED:
//   round 1's __launch_bounds__(256,8) forced a 64-VGPR cap; allocator landed
//   at 32 VGPRs and spilled ~400 B/thread (WRITE_SIZE 8 MB -> 220 MB, kernel
//   127 us). Occupancy bought with spills is a loss. (256,4) = 128-VGPR cap,
//   fits the natural ~70-100 VGPR footprint with ZERO spill, 16 waves/CU.
// Keep: int4 y-loads (15 vmem vs 40 scalar), non-temporal streaming x loads.

typedef float f32x4 __attribute__((ext_vector_type(4)));
typedef int   i32x4 __attribute__((ext_vector_type(4)));

constexpr int B = 8;
constexpr int C = 21;
constexpr int W = 512;
constexpr int H = 512;
constexpr int PIX = W * H;

__global__ __launch_bounds__(256, 4) void getweight_kernel(
    const float* __restrict__ x, const int* __restrict__ y,
    float* __restrict__ out)
{
    const int tid = blockIdx.x * blockDim.x + threadIdx.x;
    const int gpr = H / 4;        // 128 float4-groups per row
    const int gpi = W * gpr;      // 65536 groups per image
    const int b   = tid / gpi;
    const int rem = tid - b * gpi;
    const int w   = rem / gpr;
    const int h   = (rem - w * gpr) << 2;   // base h of this thread's 4 pixels

    // ---- argmax over 21 channels, 4 pixels at once ----
    // Channel 0 seeds; then 5 groups of 4 channels. Strict > keeps the FIRST
    // max index, matching jnp.argmax tie-break.
    const float* xp = x + (size_t)b * C * PIX + (size_t)w * H + h;
    f32x4 best = __builtin_nontemporal_load((const f32x4*)xp);
    int am0 = 0, am1 = 0, am2 = 0, am3 = 0;

#define ARGMAX_STEP(v, c)                                      \
    do {                                                       \
        if ((v)[0] > best[0]) { best[0] = (v)[0]; am0 = (c); } \
        if ((v)[1] > best[1]) { best[1] = (v)[1]; am1 = (c); } \
        if ((v)[2] > best[2]) { best[2] = (v)[2]; am2 = (c); } \
        if ((v)[3] > best[3]) { best[3] = (v)[3]; am3 = (c); } \
    } while (0)

#pragma unroll
    for (int g = 0; g < 5; ++g) {
        const int c0 = 4 * g + 1;
        f32x4 v0 = __builtin_nontemporal_load((const f32x4*)(xp + (size_t)(c0 + 0) * PIX));
        f32x4 v1 = __builtin_nontemporal_load((const f32x4*)(xp + (size_t)(c0 + 1) * PIX));
        f32x4 v2 = __builtin_nontemporal_load((const f32x4*)(xp + (size_t)(c0 + 2) * PIX));
        f32x4 v3 = __builtin_nontemporal_load((const f32x4*)(xp + (size_t)(c0 + 3) * PIX));
        ARGMAX_STEP(v0, c0 + 0);
        ARGMAX_STEP(v1, c0 + 1);
        ARGMAX_STEP(v2, c0 + 2);
        ARGMAX_STEP(v3, c0 + 3);
    }
#undef ARGMAX_STEP

    // ---- 5x5 neighborhood mismatch count vs y (zero-pad => OOB label 0) ----
    // Per row di: 3 aligned int4 loads covering h-4 .. h+7 (12 ints); the
    // needed window h-2 .. h+5 is elements 2..9. Out-of-range chunks become 0
    // (= pad label), exactly matching the Unfold zero-pad:
    //   chunk a (h-4..h-1) invalid iff h==0   -> needed elems h-2,h-1 OOB -> 0
    //   chunk c (h+4..h+7) invalid iff h==H-4 -> needed elems h+4,h+5 OOB -> 0
    const int* yb = y + b * PIX;
    const i32x4 zero4 = {0, 0, 0, 0};
    int cnt0 = 0, cnt1 = 0, cnt2 = 0, cnt3 = 0;
#pragma unroll
    for (int di = 0; di < 5; ++di) {
        const int ww = w + di - 2;
        const bool wok = (unsigned)ww < (unsigned)W;   // wave-uniform
        const int* yrow = yb + ww * H;
        i32x4 ca = (wok && h >= 4)       ? *(const i32x4*)(yrow + h - 4) : zero4;
        i32x4 cb = wok                   ? *(const i32x4*)(yrow + h)     : zero4;
        i32x4 cc = (wok && h <= H - 8)   ? *(const i32x4*)(yrow + h + 4) : zero4;
        const int yr[12] = {ca[0], ca[1], ca[2], ca[3],
                            cb[0], cb[1], cb[2], cb[3],
                            cc[0], cc[1], cc[2], cc[3]};
#pragma unroll
        for (int dj = 0; dj < 5; ++dj) {
            cnt0 += (yr[2 + 0 + dj] != am0) ? 1 : 0;
            cnt1 += (yr[2 + 1 + dj] != am1) ? 1 : 0;
            cnt2 += (yr[2 + 2 + dj] != am2) ? 1 : 0;
            cnt3 += (yr[2 + 3 + dj] != am3) ? 1 : 0;
        }
    }

    f32x4 res;
    res[0] = 1.0f + 1.5f * (float)cnt0;
    res[1] = 1.0f + 1.5f * (float)cnt1;
    res[2] = 1.0f + 1.5f * (float)cnt2;
    res[3] = 1.0f + 1.5f * (float)cnt3;
    __builtin_nontemporal_store(res, (f32x4*)(out + (size_t)b * PIX + (size_t)w * H + h));
}

extern "C" void kernel_launch(void* const* d_in, const int* in_sizes, int n_in,
                              void* d_out, int out_size, void* d_ws, size_t ws_size,
                              hipStream_t stream) {
    const float* x = (const float*)d_in[0];   // [8,21,512,512] f32
    const int*   y = (const int*)d_in[1];     // [8,512,512] i32
    float* out = (float*)d_out;               // [8,1,512,512] f32

    const int total_threads = B * PIX / 4;    // 524288
    const int block = 256;
    const int grid = total_threads / block;   // 2048
    getweight_kernel<<<grid, block, 0, stream>>>(x, y, out);
}

// Round 5
// 238.639 us; speedup vs baseline: 1.3373x; 1.0434x over previous
//
#include <hip/hip_runtime.h>

// GetWeightMatrix: weight = 1 + 1.5 * sum_{5x5 shifts}(y_pad != argmax_c(x))
// x: [8, 21, 512, 512] f32, y: [8, 512, 512] i32, out: [8, 1, 512, 512] f32
//
// Round 5: two-pass split. Evidence: both the round-1 spill kernel (431 MB /
// 127.5 us) and the round-4 fused kernel (~193 MB / ~56 us) sustain the SAME
// ~3.4 TB/s, while fills hit 6.7 TB/s -> the fused kernel is latency/issue-
// bound (fat footprint: 21-stream argmax + 12-int y window), not BW-bound.
// Pass 1: pure streaming argmax (~40 VGPR, 8 waves/SIMD) -> 2 MB packed u8 map
//         in d_ws. Hypothesis test: if this still caps at ~3.4 TB/s, the
//         21-channel-strided pattern itself is the DRAM-efficiency limit.
// Pass 2: 5x5 mismatch count from map + y (~18 MB traffic, L2-resident).
// Fallback: fused single kernel if ws_size < 2 MB (host-side branch, no sync).

typedef float f32x4 __attribute__((ext_vector_type(4)));
typedef int   i32x4 __attribute__((ext_vector_type(4)));

constexpr int B = 8;
constexpr int C = 21;
constexpr int W = 512;
constexpr int H = 512;
constexpr int PIX = W * H;
constexpr int NGROUP = B * PIX / 4;   // 524288 4-pixel groups

// ---------------- Pass 1: argmax over channels, 4 px/thread ----------------
__global__ __launch_bounds__(256, 8) void argmax_kernel(
    const float* __restrict__ x, unsigned int* __restrict__ amap)
{
    const int tid = blockIdx.x * blockDim.x + threadIdx.x;
    const int gpi = PIX / 4;          // 65536 groups per image (linear pixels)
    const int b   = tid / gpi;
    const int g   = tid - b * gpi;    // 4-pixel group within image

    const float* xp = x + (size_t)b * C * PIX + (size_t)g * 4;
    f32x4 best = __builtin_nontemporal_load((const f32x4*)xp);
    int am0 = 0, am1 = 0, am2 = 0, am3 = 0;

#define ARGMAX_STEP(v, c)                                      \
    do {                                                       \
        if ((v)[0] > best[0]) { best[0] = (v)[0]; am0 = (c); } \
        if ((v)[1] > best[1]) { best[1] = (v)[1]; am1 = (c); } \
        if ((v)[2] > best[2]) { best[2] = (v)[2]; am2 = (c); } \
        if ((v)[3] > best[3]) { best[3] = (v)[3]; am3 = (c); } \
    } while (0)

#pragma unroll
    for (int grp = 0; grp < 5; ++grp) {
        const int c0 = 4 * grp + 1;   // channels 1..20 in 5 groups of 4
        f32x4 v0 = __builtin_nontemporal_load((const f32x4*)(xp + (size_t)(c0 + 0) * PIX));
        f32x4 v1 = __builtin_nontemporal_load((const f32x4*)(xp + (size_t)(c0 + 1) * PIX));
        f32x4 v2 = __builtin_nontemporal_load((const f32x4*)(xp + (size_t)(c0 + 2) * PIX));
        f32x4 v3 = __builtin_nontemporal_load((const f32x4*)(xp + (size_t)(c0 + 3) * PIX));
        ARGMAX_STEP(v0, c0 + 0);
        ARGMAX_STEP(v1, c0 + 1);
        ARGMAX_STEP(v2, c0 + 2);
        ARGMAX_STEP(v3, c0 + 3);
    }
#undef ARGMAX_STEP

    // pack 4 argmax bytes (labels 0..20 fit in u8); normal store -> L2-hot for pass 2
    amap[tid] = (unsigned int)am0 | ((unsigned int)am1 << 8) |
                ((unsigned int)am2 << 16) | ((unsigned int)am3 << 24);
}

// ---------------- Pass 2: 5x5 neighborhood mismatch count ----------------
__global__ __launch_bounds__(256, 4) void weight_kernel(
    const unsigned int* __restrict__ amap, const int* __restrict__ y,
    float* __restrict__ out)
{
    const int tid = blockIdx.x * blockDim.x + threadIdx.x;
    const int gpr = H / 4;
    const int gpi = W * gpr;
    const int b   = tid / gpi;
    const int rem = tid - b * gpi;
    const int w   = rem / gpr;
    const int h   = (rem - w * gpr) << 2;

    // pass-1 linear group index == w*gpr + h/4, so same tid addresses same pixels
    const unsigned int packed = amap[tid];
    const int am0 = (int)(packed & 0xFFu);
    const int am1 = (int)((packed >> 8) & 0xFFu);
    const int am2 = (int)((packed >> 16) & 0xFFu);
    const int am3 = (int)((packed >> 24) & 0xFFu);

    const int* yb = y + b * PIX;
    const i32x4 zero4 = {0, 0, 0, 0};
    int cnt0 = 0, cnt1 = 0, cnt2 = 0, cnt3 = 0;
#pragma unroll
    for (int di = 0; di < 5; ++di) {
        const int ww = w + di - 2;
        const bool wok = (unsigned)ww < (unsigned)W;   // wave-uniform
        const int* yrow = yb + ww * H;
        // 3 aligned int4 loads cover h-4..h+7; needed window h-2..h+5 = elems 2..9.
        // OOB chunks -> 0 (= Unfold zero-pad label).
        i32x4 ca = (wok && h >= 4)     ? *(const i32x4*)(yrow + h - 4) : zero4;
        i32x4 cb = wok                 ? *(const i32x4*)(yrow + h)     : zero4;
        i32x4 cc = (wok && h <= H - 8) ? *(const i32x4*)(yrow + h + 4) : zero4;
        const int yr[12] = {ca[0], ca[1], ca[2], ca[3],
                            cb[0], cb[1], cb[2], cb[3],
                            cc[0], cc[1], cc[2], cc[3]};
#pragma unroll
        for (int dj = 0; dj < 5; ++dj) {
            cnt0 += (yr[2 + 0 + dj] != am0) ? 1 : 0;
            cnt1 += (yr[2 + 1 + dj] != am1) ? 1 : 0;
            cnt2 += (yr[2 + 2 + dj] != am2) ? 1 : 0;
            cnt3 += (yr[2 + 3 + dj] != am3) ? 1 : 0;
        }
    }

    f32x4 res;
    res[0] = 1.0f + 1.5f * (float)cnt0;
    res[1] = 1.0f + 1.5f * (float)cnt1;
    res[2] = 1.0f + 1.5f * (float)cnt2;
    res[3] = 1.0f + 1.5f * (float)cnt3;
    __builtin_nontemporal_store(res, (f32x4*)(out + (size_t)b * PIX + (size_t)w * H + h));
}

// ---------------- Fallback: fused (round-4 kernel, known-correct) ----------------
__global__ __launch_bounds__(256, 4) void getweight_fused(
    const float* __restrict__ x, const int* __restrict__ y,
    float* __restrict__ out)
{
    const int tid = blockIdx.x * blockDim.x + threadIdx.x;
    const int gpr = H / 4;
    const int gpi = W * gpr;
    const int b   = tid / gpi;
    const int rem = tid - b * gpi;
    const int w   = rem / gpr;
    const int h   = (rem - w * gpr) << 2;

    const float* xp = x + (size_t)b * C * PIX + (size_t)w * H + h;
    f32x4 best = __builtin_nontemporal_load((const f32x4*)xp);
    int am0 = 0, am1 = 0, am2 = 0, am3 = 0;
#define ARGMAX_STEP(v, c)                                      \
    do {                                                       \
        if ((v)[0] > best[0]) { best[0] = (v)[0]; am0 = (c); } \
        if ((v)[1] > best[1]) { best[1] = (v)[1]; am1 = (c); } \
        if ((v)[2] > best[2]) { best[2] = (v)[2]; am2 = (c); } \
        if ((v)[3] > best[3]) { best[3] = (v)[3]; am3 = (c); } \
    } while (0)
#pragma unroll
    for (int g = 0; g < 5; ++g) {
        const int c0 = 4 * g + 1;
        f32x4 v0 = __builtin_nontemporal_load((const f32x4*)(xp + (size_t)(c0 + 0) * PIX));
        f32x4 v1 = __builtin_nontemporal_load((const f32x4*)(xp + (size_t)(c0 + 1) * PIX));
        f32x4 v2 = __builtin_nontemporal_load((const f32x4*)(xp + (size_t)(c0 + 2) * PIX));
        f32x4 v3 = __builtin_nontemporal_load((const f32x4*)(xp + (size_t)(c0 + 3) * PIX));
        ARGMAX_STEP(v0, c0 + 0);
        ARGMAX_STEP(v1, c0 + 1);
        ARGMAX_STEP(v2, c0 + 2);
        ARGMAX_STEP(v3, c0 + 3);
    }
#undef ARGMAX_STEP

    const int* yb = y + b * PIX;
    const i32x4 zero4 = {0, 0, 0, 0};
    int cnt0 = 0, cnt1 = 0, cnt2 = 0, cnt3 = 0;
#pragma unroll
    for (int di = 0; di < 5; ++di) {
        const int ww = w + di - 2;
        const bool wok = (unsigned)ww < (unsigned)W;
        const int* yrow = yb + ww * H;
        i32x4 ca = (wok && h >= 4)     ? *(const i32x4*)(yrow + h - 4) : zero4;
        i32x4 cb = wok                 ? *(const i32x4*)(yrow + h)     : zero4;
        i32x4 cc = (wok && h <= H - 8) ? *(const i32x4*)(yrow + h + 4) : zero4;
        const int yr[12] = {ca[0], ca[1], ca[2], ca[3],
                            cb[0], cb[1], cb[2], cb[3],
                            cc[0], cc[1], cc[2], cc[3]};
#pragma unroll
        for (int dj = 0; dj < 5; ++dj) {
            cnt0 += (yr[2 + 0 + dj] != am0) ? 1 : 0;
            cnt1 += (yr[2 + 1 + dj] != am1) ? 1 : 0;
            cnt2 += (yr[2 + 2 + dj] != am2) ? 1 : 0;
            cnt3 += (yr[2 + 3 + dj] != am3) ? 1 : 0;
        }
    }

    f32x4 res;
    res[0] = 1.0f + 1.5f * (float)cnt0;
    res[1] = 1.0f + 1.5f * (float)cnt1;
    res[2] = 1.0f + 1.5f * (float)cnt2;
    res[3] = 1.0f + 1.5f * (float)cnt3;
    __builtin_nontemporal_store(res, (f32x4*)(out + (size_t)b * PIX + (size_t)w * H + h));
}

extern "C" void kernel_launch(void* const* d_in, const int* in_sizes, int n_in,
                              void* d_out, int out_size, void* d_ws, size_t ws_size,
                              hipStream_t stream) {
    const float* x = (const float*)d_in[0];   // [8,21,512,512] f32
    const int*   y = (const int*)d_in[1];     // [8,512,512] i32
    float* out = (float*)d_out;               // [8,1,512,512] f32

    const int block = 256;
    const int grid = NGROUP / block;          // 2048

    if (d_ws != nullptr && ws_size >= (size_t)NGROUP * sizeof(unsigned int)) {
        unsigned int* amap = (unsigned int*)d_ws;   // 2 MB packed argmax map
        argmax_kernel<<<grid, block, 0, stream>>>(x, amap);
        weight_kernel<<<grid, block, 0, stream>>>(amap, y, out);
    } else {
        getweight_fused<<<grid, block, 0, stream>>>(x, y, out);
    }
}